// Round 16
// baseline (84.895 us; speedup 1.0000x reference)
//
#include <hip/hip_runtime.h>
#include <stdint.h>

typedef __attribute__((ext_vector_type(8))) short bf16x8;
typedef __attribute__((ext_vector_type(4))) float f32x4;
typedef __attribute__((ext_vector_type(16))) float f32x16;
typedef unsigned short ushort_t;

#define B_ 8
#define S_ 2048
#define D_ 2048
#define E_ 8
#define J_ 128
#define M_ 32                 // s-rows per k_mid block
#define AROWS 136             // 128 lora_A + 8 gw
#define ATILE (AROWS * 64)    // shorts per k64-tile = 8704 (17 KB); 1088 chunks

static __device__ __forceinline__ unsigned short f2bf(float f) {
  union { float f; uint32_t u; } v; v.f = f;
  uint32_t u = v.u;
  return (unsigned short)((u + 0x7FFFu + ((u >> 16) & 1u)) >> 16);
}
static __device__ __forceinline__ float bf2f(ushort_t h) {
  union { uint32_t u; float f; } v; v.u = ((uint32_t)h) << 16;
  return v.f;
}
// HW packed convert: dst = {lo=bf16(a), hi=bf16(b)} (RNE)
static __device__ __forceinline__ uint32_t pkbf(float a, float b) {
  uint32_t r;
  asm("v_cvt_pk_bf16_f32 %0, %1, %2" : "=v"(r) : "v"(a), "v"(b));
  return r;
}
// conflict-free chunk swizzle (permutation of 0..7 within each 8-row group;
// disambiguates rows aliasing mod 8 -> uniform bank coverage for b128 reads)
static __device__ __forceinline__ int xswz(int row) {
  return (row & 7) ^ (((row >> 3) & 3) << 1);
}

#define GLL16(gsrc, ldst)                                                        \
  __builtin_amdgcn_global_load_lds(                                              \
      (const __attribute__((address_space(1))) void*)(gsrc),                     \
      (__attribute__((address_space(3))) void*)(ldst), 16, 0, 0)

#define SBAR() __builtin_amdgcn_sched_barrier(0)
#define VMWAIT(N)                                                                \
  do {                                                                           \
    asm volatile("s_waitcnt vmcnt(" #N ")" ::: "memory");                        \
    __builtin_amdgcn_sched_barrier(0);                                           \
  } while (0)
#define VMBAR(N)                                                                 \
  do {                                                                           \
    asm volatile("s_waitcnt vmcnt(" #N ") lgkmcnt(0)\n\ts_barrier" ::: "memory");\
    __builtin_amdgcn_sched_barrier(0);                                           \
  } while (0)

// K0: AgE[kt 0..31][row 0..135][c 0..7][8]: chunk-swizzled bf16 A_ext; storage
// chunk c holds logical chunk c ^ xswz(row). Rows: 0-127 lora_A, 128-135 gw.
// Bg[d][j] = bf16(lora_B[e][d][r]), j = e*16+r.
__global__ void k_prep(const float* __restrict__ lA, const float* __restrict__ lB,
                       const float* __restrict__ gw,
                       ushort_t* __restrict__ AgE, ushort_t* __restrict__ Bg) {
  int gid = blockIdx.x * blockDim.x + threadIdx.x;
  int stride = gridDim.x * blockDim.x;
  for (int o = gid; o < 32 * AROWS * 8; o += stride) {   // 16B chunks
    int kt = o / (AROWS * 8);
    int rem = o - kt * (AROWS * 8);
    int row = rem >> 3, c = rem & 7;
    int d = kt * 64 + (((c ^ xswz(row)) & 7) << 3);
    const float* src = (row < 128) ? (lA + (size_t)row * D_ + d)
                                   : (gw + (size_t)(row - 128) * D_ + d);
    float4 v0 = *(const float4*)src;
    float4 v1 = *(const float4*)(src + 4);
    bf16x8 outv;
    outv[0] = (short)f2bf(v0.x); outv[1] = (short)f2bf(v0.y);
    outv[2] = (short)f2bf(v0.z); outv[3] = (short)f2bf(v0.w);
    outv[4] = (short)f2bf(v1.x); outv[5] = (short)f2bf(v1.y);
    outv[6] = (short)f2bf(v1.z); outv[7] = (short)f2bf(v1.w);
    *(bf16x8*)&AgE[(size_t)o * 8] = outv;
  }
  for (int o4 = gid; o4 < (D_ * J_) / 4; o4 += stride) {
    int j4 = o4 & 31, dd = o4 >> 5;
    int e = j4 >> 2, r0 = (j4 & 3) * 4;
    float4 v = *(const float4*)(lB + ((size_t)e * D_ + dd) * 16 + r0);
    uint2 pk;
    pk.x = (uint32_t)f2bf(v.x) | ((uint32_t)f2bf(v.y) << 16);
    pk.y = (uint32_t)f2bf(v.z) | ((uint32_t)f2bf(v.w) << 16);
    ((uint2*)Bg)[o4] = pk;
  }
}

// K1: midb (bf16) = x . A^T via 32x32x16 MFMA. M=32, 512 thr (8 waves:
// jp(2) x xk(4)), grid (64,8) = 512 blocks = 2 blocks/CU -> inter-block overlap
// (m114). Per wave/iter: 1 xf + 2 af -> 2 MFMA; conflict-free xswz everywhere.
// A triple-buffered gload_lds (3/thread/iter); x fp32->reg->cvt_pk->LDS (1/iter).
// Ledger: 4 vmem/iter (x:1, A:3); steady VMWAIT(7)/VMBAR(4).
// K-partials: 3-round LDS tree. jp=0 waves compute the gw tile -> logits.
__global__ __launch_bounds__(512, 4) void k_mid(const float* __restrict__ x,
    const ushort_t* __restrict__ AgE, ushort_t* __restrict__ midb,
    float* __restrict__ lpart) {
  __shared__ ushort_t Ab[3][ATILE];   // 3 x 17 KB
  __shared__ ushort_t Xb[2][2048];    // 2 x 4 KB: 32 rows x 8 chunks, swizzled
  __shared__ float lsc[4][8];
  const int tid = threadIdx.x;
  const int w = tid >> 6, lane = tid & 63;
  const int l31 = lane & 31, hi = lane >> 5;
  const int jp = w & 1, xk = w >> 1;
  const int b = blockIdx.y, s0 = blockIdx.x * M_;
  // x mapping: thread -> row tid>>4, 4 floats at col (tid&15)*4
  const int xr = tid >> 4, xc = tid & 15;
  const float* xsrc = x + ((size_t)(b * S_ + s0 + xr)) * D_ + xc * 4;
  const int xwoff = xr * 64 + ((((xc >> 1) ^ xswz(xr)) & 7) << 3) + (xc & 1) * 4;
  const int Xs = xswz(l31);   // same for rows l31, 32+l31, jp*64+l31, 128+l31

  f32x16 acc00 = {}, acc01 = {}, acc2 = {};

  auto stageA = [&](int buf, int kt) {
    const ushort_t* base = AgE + (size_t)kt * ATILE;
    GLL16(base + (size_t)tid * 8, &Ab[buf][tid * 8]);
    GLL16(base + (size_t)(512 + tid) * 8, &Ab[buf][(512 + tid) * 8]);
    GLL16(base + (size_t)(1024 + lane) * 8, &Ab[buf][(1024 + lane) * 8]);  // gw, idempotent x8
  };
  auto loadX = [&](float4* r4, int t) {
    r4[0] = *(const float4*)(xsrc + t * 64);
  };
  auto cvtWrite = [&](int buf, const float4* r4) {
    uint2 q;
    q.x = pkbf(r4[0].x, r4[0].y);
    q.y = pkbf(r4[0].z, r4[0].w);
    *(uint2*)&Xb[buf][xwoff] = q;
  };
  auto computeTile = [&](int t, int ab) {
    const int cc = xk * 2 + hi;
    const int chs = (((cc ^ Xs) & 7) << 3);
    bf16x8 xf = *(const bf16x8*)&Xb[t & 1][l31 * 64 + chs];
    const ushort_t* Ap = &Ab[ab][(jp * 64 + l31) * 64 + chs];
    bf16x8 af0 = *(const bf16x8*)Ap;            // j jp*64+l31
    bf16x8 af1 = *(const bf16x8*)(Ap + 2048);   // j jp*64+32+l31
    acc00 = __builtin_amdgcn_mfma_f32_32x32x16_bf16(af0, xf, acc00, 0, 0, 0);
    acc01 = __builtin_amdgcn_mfma_f32_32x32x16_bf16(af1, xf, acc01, 0, 0, 0);
    if (jp == 0) {   // gw tile (A rows 128-135; C rows 8-31 unused)
      bf16x8 af2 = *(const bf16x8*)&Ab[ab][(128 + l31) * 64 + chs];
      acc2 = __builtin_amdgcn_mfma_f32_32x32x16_bf16(af2, xf, acc2, 0, 0, 0);
    }
  };

  float4 xS0[1], xS1[1];
  // prologue ledger: x(0):1, A(0):3, x(1):1, A(1):3 -> 8 outstanding
  loadX(xS0, 0); SBAR();
  stageA(0, 0);  SBAR();
  loadX(xS1, 1); SBAR();
  stageA(1, 1);  SBAR();
  VMWAIT(7);                  // drain x(0)
  cvtWrite(0, xS0);
  VMBAR(4);                   // drain A(0); keep {x(1):1, A(1):3}

  // body(T): loadX(T+2); stageA((T+2)%3); compute(T, T%3); VMWAIT(7) [drain
  // x(T+1)]; cvtWrite(T+1); VMBAR(4) [drain A(T+1), keep x(T+2)+A(T+2)]
#define BODY(T, AB, ABN, XCUR, XNXT)                                             \
  do {                                                                           \
    loadX(XNXT, (T) + 2); SBAR();                                                \
    stageA((ABN), (T) + 2); SBAR();                                              \
    computeTile((T), (AB));                                                      \
    VMWAIT(7);                                                                   \
    cvtWrite(((T) + 1) & 1, XCUR);                                               \
    VMBAR(4);                                                                    \
  } while (0)

#pragma unroll 1
  for (int k6 = 0; k6 < 5; ++k6) {
    const int t0 = 6 * k6;
    BODY(t0 + 0, 0, 2, xS1, xS0);
    BODY(t0 + 1, 1, 0, xS0, xS1);
    BODY(t0 + 2, 2, 1, xS1, xS0);
    BODY(t0 + 3, 0, 2, xS0, xS1);
    BODY(t0 + 4, 1, 0, xS1, xS0);
    BODY(t0 + 5, 2, 1, xS0, xS1);
  }
#undef BODY
  // tail: entry outstanding {x(31):1, A(31):3}
  computeTile(30, 0);
  VMWAIT(3);                  // drain x(31)
  cvtWrite(1, xS1);
  VMBAR(0);
  computeTile(31, 1);

  __syncthreads();            // compute done; Ab free for scratch

  // logits partials: jp=0 waves reduce acc2 over s (cols l31), stash per-xk
  if (jp == 0) {
#pragma unroll
    for (int q = 0; q < 4; ++q) {
      float v = acc2[q];
      v += __shfl_xor(v, 1); v += __shfl_xor(v, 2); v += __shfl_xor(v, 4);
      v += __shfl_xor(v, 8); v += __shfl_xor(v, 16);
      if (l31 == 0) lsc[xk][hi * 4 + q] = v;
    }
  }

  // 3-round deterministic K-partial reduction: xk=r dumps, xk=0 accumulates.
  float* const reg0 = (float*)&Ab[0][0];
  float* const reg1 = (float*)&Ab[1][0];
#pragma unroll 1
  for (int r = 1; r <= 3; ++r) {
    __syncthreads();
    if (xk == r) {
      float* p = jp ? reg1 : reg0;
#pragma unroll
      for (int i = 0; i < 16; ++i) {
        p[i * 64 + lane]        = acc00[i];
        p[(16 + i) * 64 + lane] = acc01[i];
      }
    }
    __syncthreads();
    if (xk == 0) {
      const float* p = jp ? reg1 : reg0;
#pragma unroll
      for (int i = 0; i < 16; ++i) {
        acc00[i] += p[i * 64 + lane];
        acc01[i] += p[(16 + i) * 64 + lane];
      }
    }
  }
  __syncthreads();

  if (xk == 0) {
    // midb store: C col(s)=l31, j-row=(q&3)+8*(q>>2)+4*hi within each 32-tile
    ushort_t* mp = midb + ((size_t)(b * S_ + s0 + l31)) * J_ + jp * 64 + 4 * hi;
#pragma unroll
    for (int G = 0; G < 4; ++G) {
      uint2 pA, pB;
      pA.x = pkbf(acc00[G * 4 + 0], acc00[G * 4 + 1]);
      pA.y = pkbf(acc00[G * 4 + 2], acc00[G * 4 + 3]);
      pB.x = pkbf(acc01[G * 4 + 0], acc01[G * 4 + 1]);
      pB.y = pkbf(acc01[G * 4 + 2], acc01[G * 4 + 3]);
      *(uint2*)&mp[G * 8] = pA;
      *(uint2*)&mp[32 + G * 8] = pB;
    }
  }
  if (w == 0 && lane < 8) {
    float s = lsc[0][lane] + lsc[1][lane] + lsc[2][lane] + lsc[3][lane];
    lpart[((size_t)(b * 64 + blockIdx.x)) * 8 + lane] = s;
  }
}

// K1.5: deterministic router. Fixed-order sum of the 64 per-block partials,
// + biases, top-2, softmax -> rinfo[b] = {i1, i2, w1, w2}.
__global__ void k_router(const float* __restrict__ lpart,
                         const float* __restrict__ tb, const float* __restrict__ mb,
                         const int* __restrict__ task_p, const int* __restrict__ mode_p,
                         float* __restrict__ rinfo) {
  __shared__ float lg[64];
  const int t = threadIdx.x;           // 64 threads
  const int b = t >> 3, e = t & 7;
  float s = 0.f;
  for (int k = 0; k < 64; ++k) s += lpart[((size_t)(b * 64 + k)) * 8 + e];
  lg[t] = s * (1.f / (float)S_) + tb[task_p[0] * E_ + e] + mb[mode_p[0] * E_ + e];
  __syncthreads();
  if (t < B_) {
    float v[8];
#pragma unroll
    for (int e2 = 0; e2 < 8; ++e2) v[e2] = lg[t * 8 + e2];
    int i1 = 0;
#pragma unroll
    for (int e2 = 1; e2 < 8; ++e2) if (v[e2] > v[i1]) i1 = e2;
    int i2 = (i1 == 0) ? 1 : 0;
#pragma unroll
    for (int e2 = 0; e2 < 8; ++e2) if (e2 != i1 && v[e2] > v[i2]) i2 = e2;
    float ex = __expf(v[i2] - v[i1]);
    float w1 = 1.f / (1.f + ex), w2 = ex * w1;
    float4 r;
    r.x = (float)i1; r.y = (float)i2; r.z = w1; r.w = w2;
    ((float4*)rinfo)[t] = r;
  }
}

// K2: out[b][s][d] = sum over 2 active experts (K=32) of mid_bf16 * (coeff*B).
__global__ __launch_bounds__(256) void k_comb(const ushort_t* __restrict__ midb,
    const float* __restrict__ rinfo, const ushort_t* __restrict__ Bg,
    float* __restrict__ out) {
  __shared__ ushort_t Bt[128][40];   // [d-row][2 experts x 16 j], +8 pad
  const int n = blockIdx.x, m = blockIdx.y, b = blockIdx.z;
  const int tid = threadIdx.x, w = tid >> 6, lane = tid & 63;
  const int lm = lane & 15, g = lane >> 4;

  const float4 ri = ((const float4*)rinfo)[b];
  const int i1 = (int)ri.x, i2 = (int)ri.y;
  const float w1 = ri.z, w2 = ri.w;

  // stage active-expert B slice, scaled by combine weight
#pragma unroll
  for (int c = 0; c < 2; ++c) {
    int ci = c * 256 + tid;
    int d = ci >> 2, sub = ci & 3;
    int e = (sub & 2) ? i2 : i1;
    float sc = (sub & 2) ? w2 : w1;
    bf16x8 bv = *(const bf16x8*)(Bg + ((size_t)(n * 128 + d)) * J_ + e * 16 + (sub & 1) * 8);
    bf16x8 bw;
#pragma unroll
    for (int i = 0; i < 8; ++i) bw[i] = (short)f2bf(bf2f((ushort_t)bv[i]) * sc);
    *(bf16x8*)&Bt[d][sub * 8] = bw;
  }

  // P fragment: raw bf16 mid loads of the active 32 j-columns
  const int srow = m * 64 + w * 16 + lm;
  const int jw = (g < 2) ? (i1 * 16 + g * 8) : (i2 * 16 + (g - 2) * 8);
  bf16x8 pf = *(const bf16x8*)&midb[((size_t)(b * S_ + srow)) * J_ + jw];
  __syncthreads();

  f32x4 acc[8] = {};
#pragma unroll
  for (int nn = 0; nn < 8; ++nn) {
    bf16x8 af = *(const bf16x8*)&Bt[nn * 16 + lm][g * 8];
    acc[nn] = __builtin_amdgcn_mfma_f32_16x16x32_bf16(af, pf, acc[nn], 0, 0, 0);
  }

  float* op = out + ((size_t)(b * S_ + srow)) * D_ + n * 128;
#pragma unroll
  for (int nn = 0; nn < 8; ++nn)
    *(f32x4*)&op[nn * 16 + g * 4] = acc[nn];
}

extern "C" void kernel_launch(void* const* d_in, const int* in_sizes, int n_in,
                              void* d_out, int out_size, void* d_ws, size_t ws_size,
                              hipStream_t stream) {
  const float* x    = (const float*)d_in[0];
  const float* gw   = (const float*)d_in[1];
  const float* tb   = (const float*)d_in[2];
  const float* mb   = (const float*)d_in[3];
  const float* lA   = (const float*)d_in[4];
  const float* lB   = (const float*)d_in[5];
  const int* task_p = (const int*)d_in[6];
  const int* mode_p = (const int*)d_in[7];
  float* out = (float*)d_out;
  char* ws = (char*)d_ws;
  ushort_t* midb = (ushort_t*)ws;                  // 4,194,304 B
  ushort_t* AgE  = (ushort_t*)(ws + 4194304);      //   557,056 B
  ushort_t* Bg   = (ushort_t*)(ws + 4751360);      //   524,288 B
  float* lpart   = (float*)(ws + 5275648);         //    16,384 B
  float* rinfo   = (float*)(ws + 5292032);         //       128 B

  hipLaunchKernelGGL(k_prep, dim3(256), dim3(256), 0, stream, lA, lB, gw, AgE, Bg);
  hipLaunchKernelGGL(k_mid, dim3(64, 8), dim3(512), 0, stream, x, AgE, midb, lpart);
  hipLaunchKernelGGL(k_router, dim3(1), dim3(64), 0, stream,
                     lpart, tb, mb, task_p, mode_p, rinfo);
  hipLaunchKernelGGL(k_comb, dim3(16, 32, 8), dim3(256), 0, stream, midb, rinfo, Bg, out);
}

// Round 17
// 79.712 us; speedup vs baseline: 1.0650x; 1.0650x over previous
//
#include <hip/hip_runtime.h>
#include <stdint.h>

typedef __attribute__((ext_vector_type(8))) short bf16x8;
typedef __attribute__((ext_vector_type(4))) float f32x4;
typedef __attribute__((ext_vector_type(16))) float f32x16;
typedef unsigned short ushort_t;

#define B_ 8
#define S_ 2048
#define D_ 2048
#define E_ 8
#define J_ 128
#define M_ 64                 // s-rows per k_mid block
#define AROWS 136             // 128 lora_A + 8 gw
#define ATILE (AROWS * 64)    // shorts per k64-tile = 8704 (17 KB); 1088 chunks
#define MIDSZ ((size_t)B_ * S_ * J_)   // shorts per midb partial slice

static __device__ __forceinline__ unsigned short f2bf(float f) {
  union { float f; uint32_t u; } v; v.f = f;
  uint32_t u = v.u;
  return (unsigned short)((u + 0x7FFFu + ((u >> 16) & 1u)) >> 16);
}
static __device__ __forceinline__ float bf2f(ushort_t h) {
  union { uint32_t u; float f; } v; v.u = ((uint32_t)h) << 16;
  return v.f;
}
// HW packed convert: dst = {lo=bf16(a), hi=bf16(b)} (RNE)
static __device__ __forceinline__ uint32_t pkbf(float a, float b) {
  uint32_t r;
  asm("v_cvt_pk_bf16_f32 %0, %1, %2" : "=v"(r) : "v"(a), "v"(b));
  return r;
}
// conflict-free chunk swizzle (permutation of 0..7 within each 8-row group;
// disambiguates rows aliasing mod 8 -> uniform bank coverage for b128 reads)
static __device__ __forceinline__ int xswz(int row) {
  return (row & 7) ^ (((row >> 3) & 3) << 1);
}

#define GLL16(gsrc, ldst)                                                        \
  __builtin_amdgcn_global_load_lds(                                              \
      (const __attribute__((address_space(1))) void*)(gsrc),                     \
      (__attribute__((address_space(3))) void*)(ldst), 16, 0, 0)

#define SBAR() __builtin_amdgcn_sched_barrier(0)
#define VMWAIT(N)                                                                \
  do {                                                                           \
    asm volatile("s_waitcnt vmcnt(" #N ")" ::: "memory");                        \
    __builtin_amdgcn_sched_barrier(0);                                           \
  } while (0)
#define VMBAR(N)                                                                 \
  do {                                                                           \
    asm volatile("s_waitcnt vmcnt(" #N ") lgkmcnt(0)\n\ts_barrier" ::: "memory");\
    __builtin_amdgcn_sched_barrier(0);                                           \
  } while (0)

// K0: AgE[kt 0..31][row 0..135][c 0..7][8]: chunk-swizzled bf16 A_ext; storage
// chunk c holds logical chunk c ^ xswz(row). Rows: 0-127 lora_A, 128-135 gw.
// Bg[d][j] = bf16(lora_B[e][d][r]), j = e*16+r.
__global__ void k_prep(const float* __restrict__ lA, const float* __restrict__ lB,
                       const float* __restrict__ gw,
                       ushort_t* __restrict__ AgE, ushort_t* __restrict__ Bg) {
  int gid = blockIdx.x * blockDim.x + threadIdx.x;
  int stride = gridDim.x * blockDim.x;
  for (int o = gid; o < 32 * AROWS * 8; o += stride) {   // 16B chunks
    int kt = o / (AROWS * 8);
    int rem = o - kt * (AROWS * 8);
    int row = rem >> 3, c = rem & 7;
    int d = kt * 64 + (((c ^ xswz(row)) & 7) << 3);
    const float* src = (row < 128) ? (lA + (size_t)row * D_ + d)
                                   : (gw + (size_t)(row - 128) * D_ + d);
    float4 v0 = *(const float4*)src;
    float4 v1 = *(const float4*)(src + 4);
    bf16x8 outv;
    outv[0] = (short)f2bf(v0.x); outv[1] = (short)f2bf(v0.y);
    outv[2] = (short)f2bf(v0.z); outv[3] = (short)f2bf(v0.w);
    outv[4] = (short)f2bf(v1.x); outv[5] = (short)f2bf(v1.y);
    outv[6] = (short)f2bf(v1.z); outv[7] = (short)f2bf(v1.w);
    *(bf16x8*)&AgE[(size_t)o * 8] = outv;
  }
  for (int o4 = gid; o4 < (D_ * J_) / 4; o4 += stride) {
    int j4 = o4 & 31, dd = o4 >> 5;
    int e = j4 >> 2, r0 = (j4 & 3) * 4;
    float4 v = *(const float4*)(lB + ((size_t)e * D_ + dd) * 16 + r0);
    uint2 pk;
    pk.x = (uint32_t)f2bf(v.x) | ((uint32_t)f2bf(v.y) << 16);
    pk.y = (uint32_t)f2bf(v.z) | ((uint32_t)f2bf(v.w) << 16);
    ((uint2*)Bg)[o4] = pk;
  }
}

// K1: midb partial (bf16) = x[:, kh*1024 .. +1023] . A^T via 32x32x16 MFMA.
// Grid (32, 8, 2): s-block x batch x K-half = 512 blocks = 2 blocks/CU.
// 512 thr, waves (jp=w&1, sp=(w>>1)&1, kk=w>>2): j-half, s-half, k-quarter-pair.
// Per wave/iter: 2 ks x {1 xf + 2 af -> 2 MFMA} = 4 MFMA (R14's interval work)
// WITH a second independent block per CU (m114 overlap). 16 iters of BK=64.
// A triple-buffered gload_lds; x fp32->reg->cvt_pk->swizzled LDS, depth 2.
// Ledger: 5 vmem/iter (x:2, A:3); steady VMWAIT(8)/VMBAR(5). 1-round K-tree.
__global__ __launch_bounds__(512, 4) void k_mid(const float* __restrict__ x,
    const ushort_t* __restrict__ AgE, ushort_t* __restrict__ midb,
    float* __restrict__ lpart) {
  __shared__ ushort_t Ab[3][ATILE];   // 3 x 17 KB
  __shared__ ushort_t Xb[2][4096];    // 2 x 8 KB: 64 rows x 8 chunks, swizzled
  __shared__ float lsc[4][8];
  const int tid = threadIdx.x;
  const int w = tid >> 6, lane = tid & 63;
  const int l31 = lane & 31, hi = lane >> 5;
  const int jp = w & 1, sp = (w >> 1) & 1, kk = w >> 2;
  const int b = blockIdx.y, s0 = blockIdx.x * M_;
  const int kh = blockIdx.z;
  // x mapping: thread -> row tid>>3, 8 floats at col kh*1024 + (tid&7)*8
  const int xr = tid >> 3;
  const float* xsrc = x + ((size_t)(b * S_ + s0 + xr)) * D_ + kh * 1024 + (tid & 7) * 8;
  const int xwoff = xr * 64 + ((((tid & 7) ^ xswz(xr)) & 7) << 3);
  const int Xs = xswz(l31);   // same for rows sp*32+l31, jp*64(+32)+l31, 128+l31
  const ushort_t* Abase = AgE + (size_t)kh * 16 * ATILE;

  f32x16 acc00 = {}, acc01 = {}, acc2 = {};

  auto stageA = [&](int buf, int t) {
    const ushort_t* base = Abase + (size_t)t * ATILE;
    GLL16(base + (size_t)tid * 8, &Ab[buf][tid * 8]);
    GLL16(base + (size_t)(512 + tid) * 8, &Ab[buf][(512 + tid) * 8]);
    GLL16(base + (size_t)(1024 + lane) * 8, &Ab[buf][(1024 + lane) * 8]);  // gw, idempotent x8
  };
  auto loadX = [&](float4* r4, int t) {
    const float* p = xsrc + t * 64;
    r4[0] = *(const float4*)(p);
    r4[1] = *(const float4*)(p + 4);
  };
  auto cvtWrite = [&](int buf, const float4* r4) {
    uint4 q;
    q.x = pkbf(r4[0].x, r4[0].y); q.y = pkbf(r4[0].z, r4[0].w);
    q.z = pkbf(r4[1].x, r4[1].y); q.w = pkbf(r4[1].z, r4[1].w);
    *(uint4*)&Xb[buf][xwoff] = q;
  };
  auto computeTile = [&](int t, int ab) {
    const int xbuf = t & 1;
#pragma unroll
    for (int k2 = 0; k2 < 2; ++k2) {
      const int ks = kk * 2 + k2;
      const int cc = ks * 2 + hi;
      const int chs = (((cc ^ Xs) & 7) << 3);
      bf16x8 xf = *(const bf16x8*)&Xb[xbuf][(sp * 32 + l31) * 64 + chs];
      const ushort_t* Ap = &Ab[ab][(jp * 64 + l31) * 64 + chs];
      bf16x8 af0 = *(const bf16x8*)Ap;            // j jp*64+l31
      bf16x8 af1 = *(const bf16x8*)(Ap + 2048);   // j jp*64+32+l31
      acc00 = __builtin_amdgcn_mfma_f32_32x32x16_bf16(af0, xf, acc00, 0, 0, 0);
      acc01 = __builtin_amdgcn_mfma_f32_32x32x16_bf16(af1, xf, acc01, 0, 0, 0);
      if (jp == 0) {   // gw tile (A rows 128-135; C rows 8-31 unused)
        bf16x8 af2 = *(const bf16x8*)&Ab[ab][(128 + l31) * 64 + chs];
        acc2 = __builtin_amdgcn_mfma_f32_32x32x16_bf16(af2, xf, acc2, 0, 0, 0);
      }
    }
  };

  float4 xS0[2], xS1[2];
  // prologue ledger: x(0):2, A(0):3, x(1):2, A(1):3 -> 10 outstanding
  loadX(xS0, 0); SBAR();
  stageA(0, 0);  SBAR();
  loadX(xS1, 1); SBAR();
  stageA(1, 1);  SBAR();
  VMWAIT(8);                  // drain x(0)
  cvtWrite(0, xS0);
  VMBAR(5);                   // drain A(0); keep {x(1):2, A(1):3}

  // body(T): loadX(T+2); stageA((T+2)%3); compute(T, T%3); VMWAIT(8) [drain
  // x(T+1)]; cvtWrite(T+1); VMBAR(5) [drain A(T+1), keep x(T+2)+A(T+2)]
#define BODY(T, AB, ABN, XCUR, XNXT)                                             \
  do {                                                                           \
    loadX(XNXT, (T) + 2); SBAR();                                                \
    stageA((ABN), (T) + 2); SBAR();                                              \
    computeTile((T), (AB));                                                      \
    VMWAIT(8);                                                                   \
    cvtWrite(((T) + 1) & 1, XCUR);                                               \
    VMBAR(5);                                                                    \
  } while (0)

  BODY(0, 0, 2, xS1, xS0);
#pragma unroll 1
  for (int k6 = 0; k6 < 2; ++k6) {
    const int t0 = 6 * k6;
    BODY(t0 + 1, 1, 0, xS0, xS1);
    BODY(t0 + 2, 2, 1, xS1, xS0);
    BODY(t0 + 3, 0, 2, xS0, xS1);
    BODY(t0 + 4, 1, 0, xS1, xS0);
    BODY(t0 + 5, 2, 1, xS0, xS1);
    BODY(t0 + 6, 0, 2, xS1, xS0);
  }
  BODY(13, 1, 0, xS0, xS1);
#undef BODY
  // tail: entry outstanding {x(15):2, A(15):3}
  computeTile(14, 2);
  VMWAIT(3);                  // drain x(15)
  cvtWrite(1, xS1);
  VMBAR(0);
  computeTile(15, 0);

  __syncthreads();            // compute done; Ab free for scratch

  // logits partials: jp=0 waves reduce acc2 over s cols, slot (sp + 2*kk)
  if (jp == 0) {
#pragma unroll
    for (int q = 0; q < 4; ++q) {
      float v = acc2[q];
      v += __shfl_xor(v, 1); v += __shfl_xor(v, 2); v += __shfl_xor(v, 4);
      v += __shfl_xor(v, 8); v += __shfl_xor(v, 16);
      if (l31 == 0) lsc[sp + 2 * kk][hi * 4 + q] = v;
    }
  }
  // 1-round K-partial reduction: kk=1 dumps to scratch, kk=0 accumulates.
  // Layout [wavepair][val][lane] -> scalar b32, bank = lane (conflict-free).
  float* const scr = (float*)&Ab[0][0];   // 32 KB (spans Ab[0..1])
  if (kk == 1) {
    float* p = scr + ((size_t)(w & 3)) * 2048;
#pragma unroll
    for (int i = 0; i < 16; ++i) {
      p[i * 64 + lane]        = acc00[i];
      p[(16 + i) * 64 + lane] = acc01[i];
    }
  }
  __syncthreads();
  if (kk == 0) {
    const float* p = scr + ((size_t)(w & 3)) * 2048;
#pragma unroll
    for (int i = 0; i < 16; ++i) {
      acc00[i] += p[i * 64 + lane];
      acc01[i] += p[(16 + i) * 64 + lane];
    }
    // midb partial store: C col(s)=l31, j-row=(q&3)+8*(q>>2)+4*hi per 32-tile
    ushort_t* mp = midb + (size_t)kh * MIDSZ +
                   ((size_t)(b * S_ + s0 + sp * 32 + l31)) * J_ + jp * 64 + 4 * hi;
#pragma unroll
    for (int G = 0; G < 4; ++G) {
      uint2 pA, pB;
      pA.x = pkbf(acc00[G * 4 + 0], acc00[G * 4 + 1]);
      pA.y = pkbf(acc00[G * 4 + 2], acc00[G * 4 + 3]);
      pB.x = pkbf(acc01[G * 4 + 0], acc01[G * 4 + 1]);
      pB.y = pkbf(acc01[G * 4 + 2], acc01[G * 4 + 3]);
      *(uint2*)&mp[G * 8] = pA;
      *(uint2*)&mp[32 + G * 8] = pB;
    }
  }
  if (w == 0 && lane < 8) {
    float s = lsc[0][lane] + lsc[1][lane] + lsc[2][lane] + lsc[3][lane];
    lpart[((size_t)(b * 64 + blockIdx.x * 2 + kh)) * 8 + lane] = s;
  }
}

// K1.5: deterministic router. Fixed-order sum of the 64 per-block partials,
// + biases, top-2, softmax -> rinfo[b] = {i1, i2, w1, w2}.
__global__ void k_router(const float* __restrict__ lpart,
                         const float* __restrict__ tb, const float* __restrict__ mb,
                         const int* __restrict__ task_p, const int* __restrict__ mode_p,
                         float* __restrict__ rinfo) {
  __shared__ float lg[64];
  const int t = threadIdx.x;           // 64 threads
  const int b = t >> 3, e = t & 7;
  float s = 0.f;
  for (int k = 0; k < 64; ++k) s += lpart[((size_t)(b * 64 + k)) * 8 + e];
  lg[t] = s * (1.f / (float)S_) + tb[task_p[0] * E_ + e] + mb[mode_p[0] * E_ + e];
  __syncthreads();
  if (t < B_) {
    float v[8];
#pragma unroll
    for (int e2 = 0; e2 < 8; ++e2) v[e2] = lg[t * 8 + e2];
    int i1 = 0;
#pragma unroll
    for (int e2 = 1; e2 < 8; ++e2) if (v[e2] > v[i1]) i1 = e2;
    int i2 = (i1 == 0) ? 1 : 0;
#pragma unroll
    for (int e2 = 0; e2 < 8; ++e2) if (e2 != i1 && v[e2] > v[i2]) i2 = e2;
    float ex = __expf(v[i2] - v[i1]);
    float w1 = 1.f / (1.f + ex), w2 = ex * w1;
    float4 r;
    r.x = (float)i1; r.y = (float)i2; r.z = w1; r.w = w2;
    ((float4*)rinfo)[t] = r;
  }
}

// K2: out[b][s][d] = sum over 2 active experts (K=32) of (mid0+mid1) * (coeff*B).
__global__ __launch_bounds__(256) void k_comb(const ushort_t* __restrict__ midb,
    const float* __restrict__ rinfo, const ushort_t* __restrict__ Bg,
    float* __restrict__ out) {
  __shared__ ushort_t Bt[128][40];   // [d-row][2 experts x 16 j], +8 pad
  const int n = blockIdx.x, m = blockIdx.y, b = blockIdx.z;
  const int tid = threadIdx.x, w = tid >> 6, lane = tid & 63;
  const int lm = lane & 15, g = lane >> 4;

  const float4 ri = ((const float4*)rinfo)[b];
  const int i1 = (int)ri.x, i2 = (int)ri.y;
  const float w1 = ri.z, w2 = ri.w;

  // stage active-expert B slice, scaled by combine weight
#pragma unroll
  for (int c = 0; c < 2; ++c) {
    int ci = c * 256 + tid;
    int d = ci >> 2, sub = ci & 3;
    int e = (sub & 2) ? i2 : i1;
    float sc = (sub & 2) ? w2 : w1;
    bf16x8 bv = *(const bf16x8*)(Bg + ((size_t)(n * 128 + d)) * J_ + e * 16 + (sub & 1) * 8);
    bf16x8 bw;
#pragma unroll
    for (int i = 0; i < 8; ++i) bw[i] = (short)f2bf(bf2f((ushort_t)bv[i]) * sc);
    *(bf16x8*)&Bt[d][sub * 8] = bw;
  }

  // P fragment: sum the two K-half partials of the active 32 j-columns
  const int srow = m * 64 + w * 16 + lm;
  const int jw = (g < 2) ? (i1 * 16 + g * 8) : (i2 * 16 + (g - 2) * 8);
  const ushort_t* mp0 = midb + ((size_t)(b * S_ + srow)) * J_ + jw;
  bf16x8 p0 = *(const bf16x8*)mp0;
  bf16x8 p1 = *(const bf16x8*)(mp0 + MIDSZ);
  bf16x8 pf;
#pragma unroll
  for (int i = 0; i < 8; ++i)
    pf[i] = (short)f2bf(bf2f((ushort_t)p0[i]) + bf2f((ushort_t)p1[i]));
  __syncthreads();

  f32x4 acc[8] = {};
#pragma unroll
  for (int nn = 0; nn < 8; ++nn) {
    bf16x8 af = *(const bf16x8*)&Bt[nn * 16 + lm][g * 8];
    acc[nn] = __builtin_amdgcn_mfma_f32_16x16x32_bf16(af, pf, acc[nn], 0, 0, 0);
  }

  float* op = out + ((size_t)(b * S_ + srow)) * D_ + n * 128;
#pragma unroll
  for (int nn = 0; nn < 8; ++nn)
    *(f32x4*)&op[nn * 16 + g * 4] = acc[nn];
}

extern "C" void kernel_launch(void* const* d_in, const int* in_sizes, int n_in,
                              void* d_out, int out_size, void* d_ws, size_t ws_size,
                              hipStream_t stream) {
  const float* x    = (const float*)d_in[0];
  const float* gw   = (const float*)d_in[1];
  const float* tb   = (const float*)d_in[2];
  const float* mb   = (const float*)d_in[3];
  const float* lA   = (const float*)d_in[4];
  const float* lB   = (const float*)d_in[5];
  const int* task_p = (const int*)d_in[6];
  const int* mode_p = (const int*)d_in[7];
  float* out = (float*)d_out;
  char* ws = (char*)d_ws;
  ushort_t* midb = (ushort_t*)ws;                  // 8,388,608 B (2 partial slices)
  ushort_t* AgE  = (ushort_t*)(ws + 8388608);      //   557,056 B
  ushort_t* Bg   = (ushort_t*)(ws + 8945664);      //   524,288 B
  float* lpart   = (float*)(ws + 9469952);         //    16,384 B
  float* rinfo   = (float*)(ws + 9486336);         //       128 B

  hipLaunchKernelGGL(k_prep, dim3(256), dim3(256), 0, stream, lA, lB, gw, AgE, Bg);
  hipLaunchKernelGGL(k_mid, dim3(32, 8, 2), dim3(512), 0, stream, x, AgE, midb, lpart);
  hipLaunchKernelGGL(k_router, dim3(1), dim3(64), 0, stream,
                     lpart, tb, mb, task_p, mode_p, rinfo);
  hipLaunchKernelGGL(k_comb, dim3(16, 32, 8), dim3(256), 0, stream, midb, rinfo, Bg, out);
}

// Round 18
// 76.559 us; speedup vs baseline: 1.1089x; 1.0412x over previous
//
#include <hip/hip_runtime.h>
#include <stdint.h>

typedef __attribute__((ext_vector_type(8))) short bf16x8;
typedef __attribute__((ext_vector_type(4))) float f32x4;
typedef __attribute__((ext_vector_type(16))) float f32x16;
typedef unsigned short ushort_t;

#define B_ 8
#define S_ 2048
#define D_ 2048
#define E_ 8
#define J_ 128
#define M_ 64                 // s-rows per k_mid block
#define AROWS 136             // 128 lora_A + 8 gw
#define ATILE (AROWS * 64)    // shorts per k64-tile = 8704 (17 KB); 1088 chunks

static __device__ __forceinline__ unsigned short f2bf(float f) {
  union { float f; uint32_t u; } v; v.f = f;
  uint32_t u = v.u;
  return (unsigned short)((u + 0x7FFFu + ((u >> 16) & 1u)) >> 16);
}
static __device__ __forceinline__ float bf2f(ushort_t h) {
  union { uint32_t u; float f; } v; v.u = ((uint32_t)h) << 16;
  return v.f;
}
// HW packed convert: dst = {lo=bf16(a), hi=bf16(b)} (RNE)
static __device__ __forceinline__ uint32_t pkbf(float a, float b) {
  uint32_t r;
  asm("v_cvt_pk_bf16_f32 %0, %1, %2" : "=v"(r) : "v"(a), "v"(b));
  return r;
}
// conflict-free chunk swizzle (permutation of 0..7 within each 8-row group;
// disambiguates rows aliasing mod 8 -> uniform bank coverage for b128 reads)
static __device__ __forceinline__ int xswz(int row) {
  return (row & 7) ^ (((row >> 3) & 3) << 1);
}

#define GLL16(gsrc, ldst)                                                        \
  __builtin_amdgcn_global_load_lds(                                              \
      (const __attribute__((address_space(1))) void*)(gsrc),                     \
      (__attribute__((address_space(3))) void*)(ldst), 16, 0, 0)

#define SBAR() __builtin_amdgcn_sched_barrier(0)
#define VMWAIT(N)                                                                \
  do {                                                                           \
    asm volatile("s_waitcnt vmcnt(" #N ")" ::: "memory");                        \
    __builtin_amdgcn_sched_barrier(0);                                           \
  } while (0)
#define VMBAR(N)                                                                 \
  do {                                                                           \
    asm volatile("s_waitcnt vmcnt(" #N ") lgkmcnt(0)\n\ts_barrier" ::: "memory");\
    __builtin_amdgcn_sched_barrier(0);                                           \
  } while (0)

// K0: AgE[kt 0..31][row 0..135][c 0..7][8]: chunk-swizzled bf16 A_ext; storage
// chunk c holds logical chunk c ^ xswz(row). Rows: 0-127 lora_A, 128-135 gw.
// Bg[d][j] = bf16(lora_B[e][d][r]), j = e*16+r.
__global__ void k_prep(const float* __restrict__ lA, const float* __restrict__ lB,
                       const float* __restrict__ gw,
                       ushort_t* __restrict__ AgE, ushort_t* __restrict__ Bg) {
  int gid = blockIdx.x * blockDim.x + threadIdx.x;
  int stride = gridDim.x * blockDim.x;
  for (int o = gid; o < 32 * AROWS * 8; o += stride) {   // 16B chunks
    int kt = o / (AROWS * 8);
    int rem = o - kt * (AROWS * 8);
    int row = rem >> 3, c = rem & 7;
    int d = kt * 64 + (((c ^ xswz(row)) & 7) << 3);
    const float* src = (row < 128) ? (lA + (size_t)row * D_ + d)
                                   : (gw + (size_t)(row - 128) * D_ + d);
    float4 v0 = *(const float4*)src;
    float4 v1 = *(const float4*)(src + 4);
    bf16x8 outv;
    outv[0] = (short)f2bf(v0.x); outv[1] = (short)f2bf(v0.y);
    outv[2] = (short)f2bf(v0.z); outv[3] = (short)f2bf(v0.w);
    outv[4] = (short)f2bf(v1.x); outv[5] = (short)f2bf(v1.y);
    outv[6] = (short)f2bf(v1.z); outv[7] = (short)f2bf(v1.w);
    *(bf16x8*)&AgE[(size_t)o * 8] = outv;
  }
  for (int o4 = gid; o4 < (D_ * J_) / 4; o4 += stride) {
    int j4 = o4 & 31, dd = o4 >> 5;
    int e = j4 >> 2, r0 = (j4 & 3) * 4;
    float4 v = *(const float4*)(lB + ((size_t)e * D_ + dd) * 16 + r0);
    uint2 pk;
    pk.x = (uint32_t)f2bf(v.x) | ((uint32_t)f2bf(v.y) << 16);
    pk.y = (uint32_t)f2bf(v.z) | ((uint32_t)f2bf(v.w) << 16);
    ((uint2*)Bg)[o4] = pk;
  }
}

// K1: midb[b][s][j] (bf16) = x . A^T via 32x32x16 MFMA.  (R14 structure: best)
// M=64, 512 thr (8 waves: jp(2) x xk(4)), grid 256 = 1 block/CU.
// Wave (jp, xk): j-half jp, K-slice ks=xk, BOTH s-tiles -> per iter 2 xf + 2 af
// reads feed 4 MFMAs (1.0 reads/MFMA). Conflict-free xswz on all LDS tiles.
// A triple-buffered gload_lds (3/thread/iter); x fp32->reg->cvt_pk->LDS (2/iter).
// Ledger: 5 vmem/iter; steady VMWAIT(8)/VMBAR(5). K-partials: 3-round LDS tree.
__global__ __launch_bounds__(512, 2) void k_mid(const float* __restrict__ x,
    const ushort_t* __restrict__ AgE, ushort_t* __restrict__ midb,
    float* __restrict__ lpart) {
  __shared__ ushort_t Ab[3][ATILE];     // 3 x 17 KB
  __shared__ ushort_t Xb[2][4096];      // 2 x 8 KB: 64 rows x 8 chunks, swizzled
  __shared__ float lsc[4][8];
  const int tid = threadIdx.x;
  const int w = tid >> 6, lane = tid & 63;
  const int l31 = lane & 31, hi = lane >> 5;
  const int jp = w & 1, xk = w >> 1;
  const int b = blockIdx.y, s0 = blockIdx.x * M_;
  // x load mapping: thread -> row tid>>3, 8 floats at col (tid&7)*8
  const int xr = tid >> 3;
  const float* xsrc = x + ((size_t)(b * S_ + s0 + xr)) * D_ + (tid & 7) * 8;
  const int xwoff = xr * 64 + ((((tid & 7) ^ xswz(xr)) & 7) << 3);
  const int Xs = xswz(l31);   // same for rows l31, 32+l31, jp*64+l31, 128+l31

  f32x16 acc00 = {}, acc01 = {}, acc10 = {}, acc11 = {}, acc2 = {};

  auto stageA = [&](int buf, int kt) {
    const ushort_t* base = AgE + (size_t)kt * ATILE;
    GLL16(base + (size_t)tid * 8, &Ab[buf][tid * 8]);
    GLL16(base + (size_t)(512 + tid) * 8, &Ab[buf][(512 + tid) * 8]);
    GLL16(base + (size_t)(1024 + lane) * 8, &Ab[buf][(1024 + lane) * 8]);  // gw rows, idempotent x8
  };
  auto loadX = [&](float4* r4, int t) {
    const float* p = xsrc + t * 64;
    r4[0] = *(const float4*)(p);
    r4[1] = *(const float4*)(p + 4);
  };
  auto cvtWrite = [&](int buf, const float4* r4) {
    uint4 q;
    q.x = pkbf(r4[0].x, r4[0].y); q.y = pkbf(r4[0].z, r4[0].w);
    q.z = pkbf(r4[1].x, r4[1].y); q.w = pkbf(r4[1].z, r4[1].w);
    *(uint4*)&Xb[buf][xwoff] = q;
  };
  auto computeTile = [&](int t, int ab) {
    const int cc = xk * 2 + hi;
    const int chs = (((cc ^ Xs) & 7) << 3);
    const ushort_t* Xp = &Xb[t & 1][l31 * 64 + chs];
    bf16x8 xf0 = *(const bf16x8*)Xp;            // s-rows  l31
    bf16x8 xf1 = *(const bf16x8*)(Xp + 2048);   // s-rows  32+l31
    const ushort_t* Ap = &Ab[ab][(jp * 64 + l31) * 64 + chs];
    bf16x8 af0 = *(const bf16x8*)Ap;            // j-rows  jp*64+l31
    bf16x8 af1 = *(const bf16x8*)(Ap + 2048);   // j-rows  jp*64+32+l31
    acc00 = __builtin_amdgcn_mfma_f32_32x32x16_bf16(af0, xf0, acc00, 0, 0, 0);
    acc10 = __builtin_amdgcn_mfma_f32_32x32x16_bf16(af0, xf1, acc10, 0, 0, 0);
    acc01 = __builtin_amdgcn_mfma_f32_32x32x16_bf16(af1, xf0, acc01, 0, 0, 0);
    acc11 = __builtin_amdgcn_mfma_f32_32x32x16_bf16(af1, xf1, acc11, 0, 0, 0);
    if (jp == 0) {   // gw tile (A rows 128-135; C rows 8-31 unused)
      bf16x8 af2 = *(const bf16x8*)&Ab[ab][(128 + l31) * 64 + chs];
      acc2 = __builtin_amdgcn_mfma_f32_32x32x16_bf16(af2, xf0, acc2, 0, 0, 0);
      acc2 = __builtin_amdgcn_mfma_f32_32x32x16_bf16(af2, xf1, acc2, 0, 0, 0);
    }
  };

  float4 xS0[2], xS1[2];
  // prologue ledger: x(0):2, A(0):3, x(1):2, A(1):3 -> 10 outstanding
  loadX(xS0, 0); SBAR();
  stageA(0, 0);  SBAR();
  loadX(xS1, 1); SBAR();
  stageA(1, 1);  SBAR();
  VMWAIT(8);                  // drain x(0)
  cvtWrite(0, xS0);
  VMBAR(5);                   // drain A(0); keep {x(1):2, A(1):3}

#define BODY(T, AB, ABN, XCUR, XNXT)                                             \
  do {                                                                           \
    loadX(XNXT, (T) + 2); SBAR();                                                \
    stageA((ABN), (T) + 2); SBAR();                                              \
    computeTile((T), (AB));                                                      \
    VMWAIT(8);                                                                   \
    cvtWrite(((T) + 1) & 1, XCUR);                                               \
    VMBAR(5);                                                                    \
  } while (0)

#pragma unroll 1
  for (int k6 = 0; k6 < 5; ++k6) {
    const int t0 = 6 * k6;
    BODY(t0 + 0, 0, 2, xS1, xS0);
    BODY(t0 + 1, 1, 0, xS0, xS1);
    BODY(t0 + 2, 2, 1, xS1, xS0);
    BODY(t0 + 3, 0, 2, xS0, xS1);
    BODY(t0 + 4, 1, 0, xS1, xS0);
    BODY(t0 + 5, 2, 1, xS0, xS1);
  }
#undef BODY
  // tail: entry outstanding {x(31):2, A(31):3}
  computeTile(30, 0);
  VMWAIT(3);                  // drain x(31)
  cvtWrite(1, xS1);
  VMBAR(0);
  computeTile(31, 1);

  __syncthreads();            // all compute done; Ab free for scratch

  // logits partials: jp=0 waves reduce acc2 over s, stash per-xk in lsc
  if (jp == 0) {
#pragma unroll
    for (int q = 0; q < 4; ++q) {
      float v = acc2[q];
      v += __shfl_xor(v, 1); v += __shfl_xor(v, 2); v += __shfl_xor(v, 4);
      v += __shfl_xor(v, 8); v += __shfl_xor(v, 16);
      if (l31 == 0) lsc[xk][hi * 4 + q] = v;
    }
  }

  // 3-round deterministic K-partial reduction: xk=r dumps, xk=0 accumulates.
  float* const reg0 = (float*)&Ab[0][0];
  float* const reg1 = (float*)&Ab[1][0];
#pragma unroll 1
  for (int r = 1; r <= 3; ++r) {
    __syncthreads();
    if (xk == r) {
      float* p = jp ? reg1 : reg0;
#pragma unroll
      for (int i = 0; i < 16; ++i) {
        p[i * 64 + lane]        = acc00[i];
        p[(16 + i) * 64 + lane] = acc01[i];
        p[(32 + i) * 64 + lane] = acc10[i];
        p[(48 + i) * 64 + lane] = acc11[i];
      }
    }
    __syncthreads();
    if (xk == 0) {
      const float* p = jp ? reg1 : reg0;
#pragma unroll
      for (int i = 0; i < 16; ++i) {
        acc00[i] += p[i * 64 + lane];
        acc01[i] += p[(16 + i) * 64 + lane];
        acc10[i] += p[(32 + i) * 64 + lane];
        acc11[i] += p[(48 + i) * 64 + lane];
      }
    }
  }
  __syncthreads();

  if (xk == 0) {
    // midb store: C col(s)=l31, j-row=(q&3)+8*(q>>2)+4*hi within each 32-tile
#pragma unroll
    for (int sp = 0; sp < 2; ++sp) {
      ushort_t* mp = midb + ((size_t)(b * S_ + s0 + sp * 32 + l31)) * J_ + jp * 64 + 4 * hi;
#pragma unroll
      for (int G = 0; G < 4; ++G) {
        uint2 pA, pB;
        if (sp == 0) {
          pA.x = pkbf(acc00[G * 4 + 0], acc00[G * 4 + 1]);
          pA.y = pkbf(acc00[G * 4 + 2], acc00[G * 4 + 3]);
          pB.x = pkbf(acc01[G * 4 + 0], acc01[G * 4 + 1]);
          pB.y = pkbf(acc01[G * 4 + 2], acc01[G * 4 + 3]);
        } else {
          pA.x = pkbf(acc10[G * 4 + 0], acc10[G * 4 + 1]);
          pA.y = pkbf(acc10[G * 4 + 2], acc10[G * 4 + 3]);
          pB.x = pkbf(acc11[G * 4 + 0], acc11[G * 4 + 1]);
          pB.y = pkbf(acc11[G * 4 + 2], acc11[G * 4 + 3]);
        }
        *(uint2*)&mp[G * 8] = pA;
        *(uint2*)&mp[32 + G * 8] = pB;
      }
    }
  }
  if (w == 0 && lane < 8) {
    float s = lsc[0][lane] + lsc[1][lane] + lsc[2][lane] + lsc[3][lane];
    lpart[((size_t)(b * 32 + blockIdx.x)) * 8 + lane] = s;
  }
}

// K2: out[b][s][d] = sum over 2 active experts (K=32) of mid_bf16 * (coeff*B).
// Router folded in: every block recomputes top-2 from lpart in a FIXED order
// (wave-uniform scalar loads -> bitwise-identical result in all blocks).
__global__ __launch_bounds__(256) void k_comb(const ushort_t* __restrict__ midb,
    const float* __restrict__ lpart, const ushort_t* __restrict__ Bg,
    const float* __restrict__ tb, const float* __restrict__ mb,
    const int* __restrict__ task_p, const int* __restrict__ mode_p,
    float* __restrict__ out) {
  __shared__ ushort_t Bt[128][40];   // [d-row][2 experts x 16 j], +8 pad
  const int n = blockIdx.x, m = blockIdx.y, b = blockIdx.z;
  const int tid = threadIdx.x, w = tid >> 6, lane = tid & 63;
  const int lm = lane & 15, g = lane >> 4;

  // inline router (deterministic, wave-uniform; scalarized by the compiler)
  float lg[8];
#pragma unroll
  for (int e = 0; e < 8; ++e) lg[e] = 0.f;
  for (int k = 0; k < 32; ++k) {
    const float* lp = lpart + ((size_t)(b * 32 + k)) * 8;
#pragma unroll
    for (int e = 0; e < 8; ++e) lg[e] += lp[e];
  }
  {
    const int ti = task_p[0], mi = mode_p[0];
#pragma unroll
    for (int e = 0; e < 8; ++e)
      lg[e] = lg[e] * (1.f / (float)S_) + tb[ti * E_ + e] + mb[mi * E_ + e];
  }
  int i1 = 0;
#pragma unroll
  for (int e = 1; e < 8; ++e) if (lg[e] > lg[i1]) i1 = e;
  int i2 = (i1 == 0) ? 1 : 0;
#pragma unroll
  for (int e = 0; e < 8; ++e) if (e != i1 && lg[e] > lg[i2]) i2 = e;
  float ex = __expf(lg[i2] - lg[i1]);
  float w1 = 1.f / (1.f + ex), w2 = ex * w1;

  // stage active-expert B slice, scaled by combine weight
#pragma unroll
  for (int c = 0; c < 2; ++c) {
    int ci = c * 256 + tid;
    int d = ci >> 2, sub = ci & 3;
    int e = (sub & 2) ? i2 : i1;
    float sc = (sub & 2) ? w2 : w1;
    bf16x8 bv = *(const bf16x8*)(Bg + ((size_t)(n * 128 + d)) * J_ + e * 16 + (sub & 1) * 8);
    bf16x8 bw;
#pragma unroll
    for (int i = 0; i < 8; ++i) bw[i] = (short)f2bf(bf2f((ushort_t)bv[i]) * sc);
    *(bf16x8*)&Bt[d][sub * 8] = bw;
  }

  // P fragment: raw bf16 mid loads of the active 32 j-columns
  const int srow = m * 64 + w * 16 + lm;
  const int jw = (g < 2) ? (i1 * 16 + g * 8) : (i2 * 16 + (g - 2) * 8);
  bf16x8 pf = *(const bf16x8*)&midb[((size_t)(b * S_ + srow)) * J_ + jw];
  __syncthreads();

  f32x4 acc[8] = {};
#pragma unroll
  for (int nn = 0; nn < 8; ++nn) {
    bf16x8 af = *(const bf16x8*)&Bt[nn * 16 + lm][g * 8];
    acc[nn] = __builtin_amdgcn_mfma_f32_16x16x32_bf16(af, pf, acc[nn], 0, 0, 0);
  }

  float* op = out + ((size_t)(b * S_ + srow)) * D_ + n * 128;
#pragma unroll
  for (int nn = 0; nn < 8; ++nn)
    *(f32x4*)&op[nn * 16 + g * 4] = acc[nn];
}

extern "C" void kernel_launch(void* const* d_in, const int* in_sizes, int n_in,
                              void* d_out, int out_size, void* d_ws, size_t ws_size,
                              hipStream_t stream) {
  const float* x    = (const float*)d_in[0];
  const float* gw   = (const float*)d_in[1];
  const float* tb   = (const float*)d_in[2];
  const float* mb   = (const float*)d_in[3];
  const float* lA   = (const float*)d_in[4];
  const float* lB   = (const float*)d_in[5];
  const int* task_p = (const int*)d_in[6];
  const int* mode_p = (const int*)d_in[7];
  float* out = (float*)d_out;
  char* ws = (char*)d_ws;
  ushort_t* midb = (ushort_t*)ws;                  // 4,194,304 B
  ushort_t* AgE  = (ushort_t*)(ws + 4194304);      //   557,056 B
  ushort_t* Bg   = (ushort_t*)(ws + 4751360);      //   524,288 B
  float* lpart   = (float*)(ws + 5275648);         //     8,192 B

  hipLaunchKernelGGL(k_prep, dim3(256), dim3(256), 0, stream, lA, lB, gw, AgE, Bg);
  hipLaunchKernelGGL(k_mid, dim3(32, 8), dim3(512), 0, stream, x, AgE, midb, lpart);
  hipLaunchKernelGGL(k_comb, dim3(16, 32, 8), dim3(256), 0, stream,
                     midb, lpart, Bg, tb, mb, task_p, mode_p, out);
}